// Round 12
// baseline (273.276 us; speedup 1.0000x reference)
//
#include <hip/hip_runtime.h>
#include <stdint.h>

// ---------------------------------------------------------------------------
// CrossAttention (b=16, c=1024, dim=1024), fp32 in/out, bf16 MFMA internally.
//   1. cvt2:   cond->CB, Wq->WQB, Wkv->WKVB (bf16)  [x NOT converted]
//   2. g_qproj: Q = x @ WQB^T  — 128^2 tiles, FUSED fp32->bf16 A-path
//               (reg-staged + swizzled ds_write; R8 wait constants)
//   3. g_kv:   KV = CB @ WKVB^T -> K, V^T   256^2 tiles (m97-plateau 920 TF)
//   4. g_s:    P' = exp(Q K^T/32) bf16 + Rpart[4][16384] partial rowsums
//              256^2 tiles (L2-resident per batch)
//   5. g_pv:   out = (P' @ V) / R           256^2 tiles
// All GEMMs: lgkm-pipelined 2-phase K-loop, counted vmcnt, XOR-swizzled LDS,
// setprio, XCD-chunked block swizzle. No-max softmax is safe: |S|<~6.
// ---------------------------------------------------------------------------

typedef __bf16 bf16_t;
typedef bf16_t bf16x8 __attribute__((ext_vector_type(8)));
typedef float f32x4 __attribute__((ext_vector_type(4)));

#define AS1 __attribute__((address_space(1)))
#define AS3 __attribute__((address_space(3)))

__device__ __forceinline__ uint16_t f2bf(float f) {
  bf16_t h = (bf16_t)f;  // RNE
  return __builtin_bit_cast(uint16_t, h);
}

// ---- fp32 -> bf16 conversion: cond + weights only ----
// float4 totals: cond 4,194,304 | wq 262,144 | wkv 524,288  => 4,980,736
__global__ __launch_bounds__(256) void cvt2(
    const float* __restrict__ c, const float* __restrict__ wq,
    const float* __restrict__ wkv, uint16_t* __restrict__ CB,
    uint16_t* __restrict__ WQB, uint16_t* __restrict__ WKVB) {
  long i = (long)blockIdx.x * 256 + threadIdx.x;
  if (i >= 4980736) return;
  const float* src;
  uint16_t* dst;
  long off;
  if (i < 4194304) { src = c; dst = CB; off = i; }
  else if (i < 4456448) { src = wq; dst = WQB; off = i - 4194304; }
  else { src = wkv; dst = WKVB; off = i - 4456448; }
  float4 v = ((const float4*)src)[off];
  ushort4 o;
  o.x = f2bf(v.x); o.y = f2bf(v.y); o.z = f2bf(v.z); o.w = f2bf(v.w);
  ((ushort4*)dst)[off] = o;
}

// ---- stage one 256x64 bf16 K-tile (32 KiB), 512 threads, 4 loads/thread ----
// LDS dest linear (global_load_lds); SOURCE chunk-XOR pre-swizzled (rule #21)
// so readers use chunk^=(row&7), conflict-free.
__device__ __forceinline__ void stage_tile(const uint16_t* __restrict__ g,
                                           int ldK, uint16_t* lds, int tid) {
#pragma unroll
  for (int i = 0; i < 4; ++i) {
    int cix = i * 512 + tid;
    int row = cix >> 3;
    int ch = cix & 7;
    int sch = ch ^ (row & 7);
    const uint16_t* gp = g + row * ldK + sch * 8;
    __builtin_amdgcn_global_load_lds((AS1 void*)gp,
                                     (AS3 void*)((uint8_t*)lds + cix * 16), 16,
                                     0, 0);
  }
}

// ---- stage one 128x64 bf16 K-tile (16 KiB), 256 threads, 4 loads/thread ----
__device__ __forceinline__ void stage128(const uint16_t* __restrict__ g,
                                         int ldK, uint16_t* lds, int tid) {
#pragma unroll
  for (int i = 0; i < 4; ++i) {
    int cix = i * 256 + tid;
    int row = cix >> 3;
    int ch = cix & 7;
    int sch = ch ^ (row & 7);
    const uint16_t* gp = g + row * ldK + sch * 8;
    __builtin_amdgcn_global_load_lds((AS1 void*)gp,
                                     (AS3 void*)((uint8_t*)lds + cix * 16), 16,
                                     0, 0);
  }
}

// ---- XCD-chunked bijective block swizzle (nwg % 8 == 0 for all grids) ----
__device__ __forceinline__ void xcd_decode(int& bx, int& by, int& bz) {
  const int gx = gridDim.x, gy = gridDim.y;
  const int nwg = gx * gy * gridDim.z;
  int fid = blockIdx.x + gx * (blockIdx.y + gy * blockIdx.z);
  int swz = (fid & 7) * (nwg >> 3) + (fid >> 3);
  bx = swz % gx;
  int rem = swz / gx;
  by = rem % gy;
  bz = rem / gy;
}

// ===========================================================================
// g_qproj: 128x128-tile GEMM, A = fp32 x (fused cvt via reg-staged ds_write).
// 4 waves, 64 KiB LDS, 2 blocks/CU. A(t+3) fp32 issued ph(t,1); converted +
// ds_written (swizzled) at ph(t+1,1); B via global_load_lds as before.
// ===========================================================================
#define ISSUE_AQ(TOFF)                                                        \
  _Pragma("unroll") for (int kq = 0; kq < 4; ++kq) {                          \
    int j = kq * 256 + tid;                                                   \
    const float* gp = At32 + (long long)(j >> 3) * K + (TOFF) + (j & 7) * 8;  \
    areg[kq][0] = *(const f32x4*)gp;                                          \
    areg[kq][1] = *(const f32x4*)(gp + 4);                                    \
  }
#define WRITE_AQ(BUF)                                                         \
  _Pragma("unroll") for (int kq = 0; kq < 4; ++kq) {                          \
    int j = kq * 256 + tid;                                                   \
    int row = j >> 3, ch = j & 7;                                             \
    bf16x8 o;                                                                 \
    o[0] = (bf16_t)areg[kq][0][0]; o[1] = (bf16_t)areg[kq][0][1];             \
    o[2] = (bf16_t)areg[kq][0][2]; o[3] = (bf16_t)areg[kq][0][3];             \
    o[4] = (bf16_t)areg[kq][1][0]; o[5] = (bf16_t)areg[kq][1][1];             \
    o[6] = (bf16_t)areg[kq][1][2]; o[7] = (bf16_t)areg[kq][1][3];             \
    *(bf16x8*)((uint8_t*)(BUF) + row * 128 + ((ch ^ (row & 7)) << 4)) = o;    \
  }

__global__ __launch_bounds__(256, 2) void g_qproj(
    const float* __restrict__ x, const uint16_t* __restrict__ B,
    uint16_t* __restrict__ C, int K, int N) {
  // u16: A0 [0,8192) A1 [8192,16384) B0 [16384,24576) B1 [24576,32768)
  __shared__ uint16_t smem[32768];

  const int tid = threadIdx.x;
  const int lane = tid & 63;
  const int wid = tid >> 6;
  const int wr = wid >> 1, wc = wid & 1;
  const int lr = lane & 15, lg = lane >> 4;
  const int ch0 = lr & 7;

  int bx, by, bz;
  xcd_decode(bx, by, bz);
  const int row0 = by * 128;
  const int col0 = bx * 128;
  const float* At32 = x + (long long)row0 * K;
  const uint16_t* Bt = B + (long long)col0 * K;

  const int NT = K >> 6;  // 16

  f32x4 areg[4][2];  // in-flight fp32 A chunks (32 VGPR)

  // ---- prologue: B(0),B(1) via gload_lds; A(0),A(1) via reg-cvt; A(2) fly --
  stage128(Bt, K, smem + 16384, tid);
  stage128(Bt + 64, K, smem + 24576, tid);
  ISSUE_AQ(0);
  WRITE_AQ(smem);                          // auto-wait drains B0,B1,A(0)
  ISSUE_AQ(64);
  WRITE_AQ((uint8_t*)smem + 16384);        // buf A1; auto-wait drains A(1)
  if (NT > 2) ISSUE_AQ(128);               // A(2) stays in flight
  asm volatile("s_waitcnt lgkmcnt(0)" ::: "memory");  // ds_writes visible
  __builtin_amdgcn_s_barrier();

  f32x4 acc[4][4] = {};
  bf16x8 aA_[2][2], aB_[2][2], bF[4][2];

  {
    const uint8_t* sa = (const uint8_t*)smem;
#pragma unroll
    for (int mi = 0; mi < 2; ++mi)
#pragma unroll
      for (int kk = 0; kk < 2; ++kk)
        aA_[mi][kk] = *(const bf16x8*)(sa + (wr * 64 + mi * 16 + lr) * 128 +
                                       (((kk * 4 + lg) ^ ch0) << 4));
  }

  for (int t = 0; t < NT; ++t) {
    const uint8_t* sa = (const uint8_t*)(smem + (t & 1) * 8192);
    const uint8_t* sb = (const uint8_t*)(smem + 16384 + (t & 1) * 8192);

    // phase (t,0): MFMA {aA_, bF}; prefetch aB_ (stays lgkm-outstanding)
#pragma unroll
    for (int nj = 0; nj < 4; ++nj)
#pragma unroll
      for (int kk = 0; kk < 2; ++kk)
        bF[nj][kk] = *(const bf16x8*)(sb + (wc * 64 + nj * 16 + lr) * 128 +
                                      (((kk * 4 + lg) ^ ch0) << 4));
#pragma unroll
    for (int mi = 0; mi < 2; ++mi)
#pragma unroll
      for (int kk = 0; kk < 2; ++kk)
        aB_[mi][kk] = *(const bf16x8*)(sa + (wr * 64 + 32 + mi * 16 + lr) * 128 +
                                       (((kk * 4 + lg) ^ ch0) << 4));
    __builtin_amdgcn_s_setprio(1);
#pragma unroll
    for (int kk = 0; kk < 2; ++kk)
#pragma unroll
      for (int mi = 0; mi < 2; ++mi)
#pragma unroll
        for (int nj = 0; nj < 4; ++nj)
          acc[mi][nj] = __builtin_amdgcn_mfma_f32_16x16x32_bf16(
              aA_[mi][kk], bF[nj][kk], acc[mi][nj], 0, 0, 0);
    __builtin_amdgcn_s_setprio(0);
    // WAR: drain aB_/bF reads of buf[t&1] before ph(t,1) writes into it
    asm volatile("s_waitcnt lgkmcnt(0)" ::: "memory");
    __builtin_amdgcn_s_barrier();

    // phase (t,1): A-write(t+2) + A-issue(t+3) + B-stage(t+2); MFMA {aB_};
    // refill aA_(t+1). FIFO entering: [A(t+2)x8, B(t+1)x4].
    if (t + 2 < NT) WRITE_AQ((uint8_t*)smem + (t & 1) * 16384);
    if (t + 3 < NT) ISSUE_AQ((t + 3) * 64);
    if (t + 2 < NT)
      stage128(Bt + (t + 2) * 64, K, smem + 16384 + (t & 1) * 8192, tid);
    if (t + 1 < NT) {
      const uint8_t* sa2 = (const uint8_t*)(smem + ((t + 1) & 1) * 8192);
#pragma unroll
      for (int mi = 0; mi < 2; ++mi)
#pragma unroll
        for (int kk = 0; kk < 2; ++kk)
          aA_[mi][kk] = *(const bf16x8*)(sa2 + (wr * 64 + mi * 16 + lr) * 128 +
                                         (((kk * 4 + lg) ^ ch0) << 4));
    }
    __builtin_amdgcn_s_setprio(1);
#pragma unroll
    for (int kk = 0; kk < 2; ++kk)
#pragma unroll
      for (int mi = 0; mi < 2; ++mi)
#pragma unroll
        for (int nj = 0; nj < 4; ++nj)
          acc[2 + mi][nj] = __builtin_amdgcn_mfma_f32_16x16x32_bf16(
              aB_[mi][kk], bF[nj][kk], acc[2 + mi][nj], 0, 0, 0);
    __builtin_amdgcn_s_setprio(0);
    // derived counted wait: complete B(t+1) (bF of next phase); leave rest.
    if (t + 3 < NT)       // [B(t+1):4, A(t+3):8, B(t+2):4]
      asm volatile("s_waitcnt vmcnt(12)" ::: "memory");
    else if (t + 2 < NT)  // [B(t+1):4, B(t+2):4]
      asm volatile("s_waitcnt vmcnt(4)" ::: "memory");
    else if (t + 1 < NT)  // [B(t+1):4]
      asm volatile("s_waitcnt vmcnt(0)" ::: "memory");
    __builtin_amdgcn_s_barrier();
  }

#pragma unroll
  for (int mi = 0; mi < 4; ++mi)
#pragma unroll
    for (int ni = 0; ni < 4; ++ni) {
      const int row = row0 + wr * 64 + mi * 16 + lg * 4;
      const int col = col0 + wc * 64 + ni * 16 + lr;
#pragma unroll
      for (int j = 0; j < 4; ++j)
        C[(long long)(row + j) * N + col] = f2bf(acc[mi][ni][j]);
    }
}

// ===========================================================================
// 256x256-tile body (8 waves, 128 KiB LDS) — shared by g_kv / g_s / g_pv.
// EPI 1: kv-split (col<1024 -> K; col>=1024 -> V^T via LDS transpose)
// EPI 3: P' = exp(acc*scale) bf16 + Rpart[bx][grow] partial rowsums
// EPI 4: C fp32 = acc / R (R = sum of 4 Rpart)
// ===========================================================================
template <int EPI>
__device__ __forceinline__ void gemm256_body(
    const uint16_t* __restrict__ A, const uint16_t* __restrict__ B,
    void* __restrict__ C0, void* __restrict__ C1, float* __restrict__ Rpart,
    int K, float scale) {
  __shared__ uint16_t smem[65536];
  __shared__ float RLDS[256];

  const int tid = threadIdx.x;
  const int lane = tid & 63;
  const int wid = tid >> 6;
  const int wr = wid >> 2;    // 0..1
  const int wc = wid & 3;     // 0..3
  const int lr = lane & 15, lg = lane >> 4;
  const int ch0 = lr & 7;

  int bx, by, bz;
  xcd_decode(bx, by, bz);
  const int row0 = by * 256;
  const int col0 = bx * 256;
  const long long sAB = (EPI == 1) ? 0ll : 1048576ll;
  const uint16_t* At = A + (long long)bz * sAB + (long long)row0 * K;
  const uint16_t* Bt = B + (long long)bz * sAB + (long long)col0 * K;
  const int grow0 = bz * 1024 + row0;  // global row for Rpart (EPI 3/4)

  const int NT = K >> 6;

  if (EPI == 4) {  // stage 1/R (Rpart complete from prior kernel)
    if (tid < 256) {
      float r = 0.f;
#pragma unroll
      for (int p = 0; p < 4; ++p) r += Rpart[p * 16384 + grow0 + tid];
      RLDS[tid] = 1.0f / r;
    }
  }

  stage_tile(At, K, smem, tid);
  stage_tile(Bt, K, smem + 32768, tid);
  stage_tile(At + 64, K, smem + 16384, tid);
  stage_tile(Bt + 64, K, smem + 49152, tid);
  asm volatile("s_waitcnt vmcnt(8)" ::: "memory");
  __builtin_amdgcn_s_barrier();

  f32x4 acc[8][4] = {};
  bf16x8 aA_[4][2], aB_[4][2], bF[4][2];

  {
    const uint8_t* sa = (const uint8_t*)smem;
#pragma unroll
    for (int mi = 0; mi < 4; ++mi)
#pragma unroll
      for (int kk = 0; kk < 2; ++kk)
        aA_[mi][kk] = *(const bf16x8*)(sa + (wr * 128 + mi * 16 + lr) * 128 +
                                       (((kk * 4 + lg) ^ ch0) << 4));
  }

  for (int t = 0; t < NT; ++t) {
    const uint8_t* sa = (const uint8_t*)(smem + (t & 1) * 16384);
    const uint8_t* sb = (const uint8_t*)(smem + 32768 + (t & 1) * 16384);

#pragma unroll
    for (int nj = 0; nj < 4; ++nj)
#pragma unroll
      for (int kk = 0; kk < 2; ++kk)
        bF[nj][kk] = *(const bf16x8*)(sb + (wc * 64 + nj * 16 + lr) * 128 +
                                      (((kk * 4 + lg) ^ ch0) << 4));
#pragma unroll
    for (int mi = 0; mi < 4; ++mi)
#pragma unroll
      for (int kk = 0; kk < 2; ++kk)
        aB_[mi][kk] = *(const bf16x8*)(sa + (wr * 128 + 64 + mi * 16 + lr) * 128 +
                                       (((kk * 4 + lg) ^ ch0) << 4));
    __builtin_amdgcn_s_setprio(1);
#pragma unroll
    for (int kk = 0; kk < 2; ++kk)
#pragma unroll
      for (int mi = 0; mi < 4; ++mi)
#pragma unroll
        for (int nj = 0; nj < 4; ++nj)
          acc[mi][nj] = __builtin_amdgcn_mfma_f32_16x16x32_bf16(
              aA_[mi][kk], bF[nj][kk], acc[mi][nj], 0, 0, 0);
    __builtin_amdgcn_s_setprio(0);
    if (t + 1 < NT) asm volatile("s_waitcnt vmcnt(4)" ::: "memory");
    asm volatile("s_waitcnt lgkmcnt(0)" ::: "memory");
    __builtin_amdgcn_s_barrier();

    if (t + 2 < NT) {
      stage_tile(At + (t + 2) * 64, K, smem + (t & 1) * 16384, tid);
      stage_tile(Bt + (t + 2) * 64, K, smem + 32768 + (t & 1) * 16384, tid);
    }
    if (t + 1 < NT) {
      const uint8_t* sa2 = (const uint8_t*)(smem + ((t + 1) & 1) * 16384);
#pragma unroll
      for (int mi = 0; mi < 4; ++mi)
#pragma unroll
        for (int kk = 0; kk < 2; ++kk)
          aA_[mi][kk] = *(const bf16x8*)(sa2 + (wr * 128 + mi * 16 + lr) * 128 +
                                         (((kk * 4 + lg) ^ ch0) << 4));
    }
    __builtin_amdgcn_s_setprio(1);
#pragma unroll
    for (int kk = 0; kk < 2; ++kk)
#pragma unroll
      for (int mi = 0; mi < 4; ++mi)
#pragma unroll
        for (int nj = 0; nj < 4; ++nj)
          acc[4 + mi][nj] = __builtin_amdgcn_mfma_f32_16x16x32_bf16(
              aB_[mi][kk], bF[nj][kk], acc[4 + mi][nj], 0, 0, 0);
    __builtin_amdgcn_s_setprio(0);
    if (t + 2 < NT)
      asm volatile("s_waitcnt vmcnt(8)" ::: "memory");
    else
      asm volatile("s_waitcnt vmcnt(0)" ::: "memory");
    __builtin_amdgcn_s_barrier();
  }

  // ---- epilogue: C/D layout col=lane&15, row=(lane>>4)*4+j ----
  if (EPI == 1) {
    if (col0 >= 1024) {  // V^T via LDS transpose
      __syncthreads();
#pragma unroll
      for (int mi = 0; mi < 8; ++mi)
#pragma unroll
        for (int ni = 0; ni < 4; ++ni) {
          const int cc = wc * 64 + ni * 16 + lr;
          const int jjb = wr * 128 + mi * 16 + lg * 4;
          ushort4 o;
          o.x = f2bf(acc[mi][ni][0]);
          o.y = f2bf(acc[mi][ni][1]);
          o.z = f2bf(acc[mi][ni][2]);
          o.w = f2bf(acc[mi][ni][3]);
          *(ushort4*)&smem[cc * 256 + (jjb ^ ((cc & 7) << 3))] = o;
        }
      __syncthreads();
      const int b = row0 >> 10, jj0 = row0 & 1023;
      uint16_t* Vp = (uint16_t*)C1;
#pragma unroll
      for (int k = 0; k < 16; ++k) {
        const int cc = k * 16 + (tid >> 5);
        const int jb = (tid & 31) * 8;
        bf16x8 v = *(const bf16x8*)&smem[cc * 256 + (jb ^ ((cc & 7) << 3))];
        *(bf16x8*)(Vp + (long long)b * 1048576 +
                   (long long)(col0 - 1024 + cc) * 1024 + jj0 + jb) = v;
      }
      return;
    }
    uint16_t* Kp = (uint16_t*)C0;
#pragma unroll
    for (int mi = 0; mi < 8; ++mi)
#pragma unroll
      for (int ni = 0; ni < 4; ++ni) {
        const int row = row0 + wr * 128 + mi * 16 + lg * 4;
        const int col = col0 + wc * 64 + ni * 16 + lr;
#pragma unroll
        for (int j = 0; j < 4; ++j)
          Kp[(long long)(row + j) * 1024 + col] = f2bf(acc[mi][ni][j]);
      }
  } else if (EPI == 3) {
    // P' = exp(acc*scale) -> bf16; partial row sums -> Rpart[bx][grow]
    uint16_t* Pp = (uint16_t*)C0 + (long long)bz * 1048576;
    float rs[8][4];
#pragma unroll
    for (int mi = 0; mi < 8; ++mi) {
#pragma unroll
      for (int j = 0; j < 4; ++j) rs[mi][j] = 0.f;
#pragma unroll
      for (int ni = 0; ni < 4; ++ni) {
        const int row = row0 + wr * 128 + mi * 16 + lg * 4;
        const int col = col0 + wc * 64 + ni * 16 + lr;
#pragma unroll
        for (int j = 0; j < 4; ++j) {
          float e = __expf(acc[mi][ni][j] * scale);
          Pp[(long long)(row + j) * 1024 + col] = f2bf(e);
          rs[mi][j] += e;
        }
      }
    }
#pragma unroll
    for (int o = 1; o < 16; o <<= 1)
#pragma unroll
      for (int mi = 0; mi < 8; ++mi)
#pragma unroll
        for (int j = 0; j < 4; ++j) rs[mi][j] += __shfl_xor(rs[mi][j], o, 64);
    __syncthreads();
    float* RS = (float*)smem;  // [4][256]
    if (lr == 0) {
#pragma unroll
      for (int mi = 0; mi < 8; ++mi)
#pragma unroll
        for (int j = 0; j < 4; ++j)
          RS[wc * 256 + wr * 128 + mi * 16 + lg * 4 + j] = rs[mi][j];
    }
    __syncthreads();
    if (tid < 256)
      Rpart[bx * 16384 + grow0 + tid] =
          RS[tid] + RS[256 + tid] + RS[512 + tid] + RS[768 + tid];
  } else {  // EPI == 4
    float* C = (float*)C0;
#pragma unroll
    for (int mi = 0; mi < 8; ++mi)
#pragma unroll
      for (int ni = 0; ni < 4; ++ni) {
        const int row = row0 + wr * 128 + mi * 16 + lg * 4;
        const int col = col0 + wc * 64 + ni * 16 + lr;
#pragma unroll
        for (int j = 0; j < 4; ++j) {
          const float rinv = RLDS[wr * 128 + mi * 16 + lg * 4 + j];
          C[(long long)bz * 1048576 + (long long)(row + j) * 1024 + col] =
              acc[mi][ni][j] * rinv;
        }
      }
  }
}

// ---- named GEMM sites ----
__global__ __launch_bounds__(512, 2) void g_kv(const uint16_t* A,
                                               const uint16_t* B, uint16_t* Kp,
                                               uint16_t* Vp, int K) {
  gemm256_body<1>(A, B, Kp, Vp, nullptr, K, 1.0f);
}
__global__ __launch_bounds__(512, 2) void g_s(const uint16_t* A,
                                              const uint16_t* B, uint16_t* Pp,
                                              float* Rpart, int K,
                                              float scale) {
  gemm256_body<3>(A, B, Pp, nullptr, Rpart, K, scale);
}
__global__ __launch_bounds__(512, 2) void g_pv(const uint16_t* A,
                                               const uint16_t* B, float* C,
                                               float* Rpart, int K) {
  gemm256_body<4>(A, B, C, nullptr, Rpart, K, 1.0f);
}

extern "C" void kernel_launch(void* const* d_in, const int* in_sizes, int n_in,
                              void* d_out, int out_size, void* d_ws, size_t ws_size,
                              hipStream_t stream) {
  const float* x    = (const float*)d_in[0];
  const float* cond = (const float*)d_in[1];
  const float* Wq   = (const float*)d_in[2];
  const float* Wkv  = (const float*)d_in[3];
  float* out = (float*)d_out;

  uint8_t* ws = (uint8_t*)d_ws;
  const long long MiB = 1ll << 20;
  // layout: Pp 0-32 (P', written by g_s), CB 32-64 (Rpart overlays CB's head
  // after g_kv), WQB 64, WKVB 66, Q 70, Kb 102, VT 134.
  uint16_t* Pp    = (uint16_t*)(ws + 0 * MiB);
  uint16_t* CB    = (uint16_t*)(ws + 32 * MiB);
  float*    Rpart = (float*)(ws + 32 * MiB);     // 256 KiB, CB dead by g_s
  uint16_t* WQB   = (uint16_t*)(ws + 64 * MiB);
  uint16_t* WKVB  = (uint16_t*)(ws + 66 * MiB);
  uint16_t* Q     = (uint16_t*)(ws + 70 * MiB);
  uint16_t* Kb    = (uint16_t*)(ws + 102 * MiB);
  uint16_t* VT    = (uint16_t*)(ws + 134 * MiB);

  // 1. conversions (cond + weights only): 4,980,736 float4 / 256 = 19456
  cvt2<<<19456, 256, 0, stream>>>(cond, Wq, Wkv, CB, WQB, WKVB);

  // 2. Q = x @ WQB^T (fused fp32-A cvt), 1024 blocks, 2/CU
  g_qproj<<<dim3(8, 128), 256, 0, stream>>>(x, WQB, Q, 1024, 1024);
  // 3. KV = CB @ WKVB^T -> K, V^T (512 blocks, 2/CU)
  g_kv<<<dim3(8, 64), 512, 0, stream>>>(CB, WKVB, Kb, VT, 1024);
  // 4. P' = exp(Q K^T / 32) + Rpart (256 blocks, 256^2 tiles)
  g_s<<<dim3(4, 4, 16), 512, 0, stream>>>(Q, Kb, Pp, Rpart, 1024, 0.03125f);
  // 5. out = (P' @ V) / R (256 blocks, 256^2 tiles)
  g_pv<<<dim3(4, 4, 16), 512, 0, stream>>>(Pp, VT, out, Rpart, 1024);
}

// Round 14
// 241.607 us; speedup vs baseline: 1.1311x; 1.1311x over previous
//
#include <hip/hip_runtime.h>
#include <stdint.h>

// ---------------------------------------------------------------------------
// CrossAttention (b=16, c=1024, dim=1024), fp32 in/out, bf16 MFMA internally.
//   1. cvt_all: x->XB, cond->CB, Wq->WQB, Wkv->WKVB (bf16)
//   2. g_qproj: Q = XB @ WQB^T            128^2 tiles, 1024 blocks
//   3. g_kv:    KV = CB @ WKVB^T -> K,V^T 256^2 tiles, 8-PHASE schedule
//   4. g_s:     P' = exp(Q K^T/32), Rpart[8][16384] partial rowsums (128^2)
//   5. g_pv:    out = (P' @ V) / R        (128^2)
// R14 = R13 with the bQ-clobber bug fixed: B fragments must live in
// bAll[4][2] across the 4 phases of a tile (ph2's MFMA(H1,N2=0) reuses B
// loaded at ph0; R13's 2-wide bQ held N2=1 there -> wrong products).
// Stage leads/waits unchanged (audited sound): every half staged >=3.5
// phases before first read; vmcnt(4) at ph3/ph7 completes exactly the next
// window's tile and leaves 4 loads flying.
// ---------------------------------------------------------------------------

typedef __bf16 bf16_t;
typedef bf16_t bf16x8 __attribute__((ext_vector_type(8)));
typedef float f32x4 __attribute__((ext_vector_type(4)));

#define AS1 __attribute__((address_space(1)))
#define AS3 __attribute__((address_space(3)))

__device__ __forceinline__ uint16_t f2bf(float f) {
  bf16_t h = (bf16_t)f;  // RNE
  return __builtin_bit_cast(uint16_t, h);
}

// ---- fused fp32 -> bf16 conversion for all 4 tensors, float4-vectorized ----
// total float4 = (16777216 + 16777216 + 1048576 + 2097152)/4 = 9,175,040
__global__ __launch_bounds__(256) void cvt_all(
    const float* __restrict__ x, const float* __restrict__ c,
    const float* __restrict__ wq, const float* __restrict__ wkv,
    uint16_t* __restrict__ XB, uint16_t* __restrict__ CB,
    uint16_t* __restrict__ WQB, uint16_t* __restrict__ WKVB) {
  long i = (long)blockIdx.x * 256 + threadIdx.x;
  if (i >= 9175040) return;
  const float* src;
  uint16_t* dst;
  long off;
  if (i < 4194304) { src = x; dst = XB; off = i; }
  else if (i < 8388608) { src = c; dst = CB; off = i - 4194304; }
  else if (i < 8650752) { src = wq; dst = WQB; off = i - 8388608; }
  else { src = wkv; dst = WKVB; off = i - 8650752; }
  float4 v = ((const float4*)src)[off];
  ushort4 o;
  o.x = f2bf(v.x); o.y = f2bf(v.y); o.z = f2bf(v.z); o.w = f2bf(v.w);
  ((ushort4*)dst)[off] = o;
}

// ---- stage one 128x64 bf16 HALF-tile (16 KiB), 512 threads, 2 loads ----
// LDS dest linear (global_load_lds); SOURCE chunk-XOR pre-swizzled (rule #21)
// so readers use chunk^=(row&7), conflict-free.
__device__ __forceinline__ void stage_half(const uint16_t* __restrict__ g,
                                           int ldK, uint16_t* lds, int tid) {
#pragma unroll
  for (int i = 0; i < 2; ++i) {
    int c = i * 512 + tid;              // 16B-chunk index, 0..1023
    int row = c >> 3;                   // 0..127
    int ch = c & 7;
    int sch = ch ^ (row & 7);
    const uint16_t* gp = g + row * ldK + sch * 8;
    __builtin_amdgcn_global_load_lds((AS1 void*)gp,
                                     (AS3 void*)((uint8_t*)lds + c * 16), 16,
                                     0, 0);
  }
}

// ---- stage one 128x64 bf16 K-tile (16 KiB), 256 threads, 4 loads/thread ----
__device__ __forceinline__ void stage128(const uint16_t* __restrict__ g,
                                         int ldK, uint16_t* lds, int tid) {
#pragma unroll
  for (int i = 0; i < 4; ++i) {
    int cix = i * 256 + tid;
    int row = cix >> 3;
    int ch = cix & 7;
    int sch = ch ^ (row & 7);
    const uint16_t* gp = g + row * ldK + sch * 8;
    __builtin_amdgcn_global_load_lds((AS1 void*)gp,
                                     (AS3 void*)((uint8_t*)lds + cix * 16), 16,
                                     0, 0);
  }
}

// ---- XCD-chunked bijective block swizzle (nwg % 8 == 0 for all grids) ----
__device__ __forceinline__ void xcd_decode(int& bx, int& by, int& bz) {
  const int gx = gridDim.x, gy = gridDim.y;
  const int nwg = gx * gy * gridDim.z;
  int fid = blockIdx.x + gx * (blockIdx.y + gy * blockIdx.z);
  int swz = (fid & 7) * (nwg >> 3) + (fid >> 3);
  bx = swz % gx;
  int rem = swz / gx;
  by = rem % gy;
  bz = rem / gy;
}

// ===========================================================================
// g_kv: 256x256 tile, 8 waves, 128 KiB LDS, 8-PHASE schedule.
// Iteration i: tiles t0=2i (buf0, ph0-3) and t1=2i+1 (buf1, ph4-7).
// Per phase: {ds_reads | stage ONE half | BAR | lgkm0 | prio1 16xMFMA prio0 |
// [vmcnt(4) at ph3/ph7] | BAR}.  B lives in bAll[4][2] across the tile.
//   ph0: rdA(H0)+rdB(N2=0); stage buf1.A-lo <- t1
//   ph1: rdB(N2=1);         stage buf1.A-hi <- t1
//   ph2: rdA(H1);           stage buf0.B-lo <- t0+2
//   ph3: (none);            stage buf0.B-hi <- t0+2; vmcnt(4) completes t1
//   ph4-7: same on buf1, staging buf0.A <- t0+2 / buf1.B <- t1+2;
//   ph7 vmcnt(4) completes t0+2, leaves t1+2.B flying.
// ===========================================================================
#define KV_RD_A(BASE, H)                                                      \
  _Pragma("unroll") for (int mi = 0; mi < 4; ++mi)                            \
      _Pragma("unroll") for (int kk = 0; kk < 2; ++kk)                        \
          aF[mi][kk] = *(const bf16x8*)((BASE) + ((H)*64 + mi*16 + lr)*128 +  \
                                        (((kk*4 + lg) ^ ch0) << 4));
#define KV_RD_B(BASE, N2)                                                     \
  _Pragma("unroll") for (int nj = 0; nj < 2; ++nj)                            \
      _Pragma("unroll") for (int kk = 0; kk < 2; ++kk)                        \
          bAll[(N2)*2 + nj][kk] = *(const bf16x8*)(                           \
              (BASE) + ((wc & 1)*64 + ((N2)*2 + nj)*16 + lr)*128 +            \
              (((kk*4 + lg) ^ ch0) << 4));
#define KV_MFMA(H, N2)                                                        \
  __builtin_amdgcn_s_setprio(1);                                              \
  _Pragma("unroll") for (int kk = 0; kk < 2; ++kk)                            \
      _Pragma("unroll") for (int mi = 0; mi < 4; ++mi)                        \
          _Pragma("unroll") for (int nj = 0; nj < 2; ++nj)                    \
              acc[(H)*4 + mi][(N2)*2 + nj] =                                  \
                  __builtin_amdgcn_mfma_f32_16x16x32_bf16(                    \
                      aF[mi][kk], bAll[(N2)*2 + nj][kk],                      \
                      acc[(H)*4 + mi][(N2)*2 + nj], 0, 0, 0);                 \
  __builtin_amdgcn_s_setprio(0);
#define KV_BAR __builtin_amdgcn_s_barrier()
#define KV_LGKM0 asm volatile("s_waitcnt lgkmcnt(0)" ::: "memory")

__global__ __launch_bounds__(512) void g_kv(
    const uint16_t* __restrict__ A, const uint16_t* __restrict__ B,
    uint16_t* __restrict__ Kp, uint16_t* __restrict__ Vp, int K) {
  __shared__ uint16_t As[2][2][8192];  // [buf][half(rows h*128..)][128x64]
  __shared__ uint16_t Bs[2][2][8192];  // [buf][half(cols h*128..)][128x64]

  const int tid = threadIdx.x;
  const int lane = tid & 63;
  const int wid = tid >> 6;
  const int wr = wid >> 2;    // 0..1 : M wave row (128 rows)
  const int wc = wid & 3;     // 0..3 : N wave col (64 cols)
  const int lr = lane & 15, lg = lane >> 4;
  const int ch0 = lr & 7;

  int bx, by, bz;
  xcd_decode(bx, by, bz);
  const int row0 = by * 256;
  const int col0 = bx * 256;
  const uint16_t* At = A + (long long)row0 * K;
  const uint16_t* Bt = B + (long long)col0 * K;

  const int NT = K >> 6;    // 16 tiles
  const int NIT = NT >> 1;  // 8 iterations

  // ---- prologue: t0 full (4 halves) + t1.B (2 halves); vmcnt(4) ----
  stage_half(Bt, K, &Bs[0][0][0], tid);
  stage_half(Bt + 128 * K, K, &Bs[0][1][0], tid);
  stage_half(At, K, &As[0][0][0], tid);
  stage_half(At + 128 * K, K, &As[0][1][0], tid);
  stage_half(Bt + 64, K, &Bs[1][0][0], tid);
  stage_half(Bt + 128 * K + 64, K, &Bs[1][1][0], tid);
  asm volatile("s_waitcnt vmcnt(4)" ::: "memory");  // t0 landed; t1.B flies
  KV_BAR;

  f32x4 acc[8][4] = {};
  bf16x8 aF[4][2];    // current (H) A fragments
  bf16x8 bAll[4][2];  // ALL 4 ni B fragments of current tile (lives 4 phases)

  for (int i = 0; i < NIT; ++i) {
    const int t1 = 2 * i + 1, tn0 = 2 * i + 2, tn1 = 2 * i + 3;
    const uint8_t* a0 = (const uint8_t*)&As[0][wr][0];
    const uint8_t* a1 = (const uint8_t*)&As[1][wr][0];
    const uint8_t* b0 = (const uint8_t*)&Bs[0][wc >> 1][0];
    const uint8_t* b1 = (const uint8_t*)&Bs[1][wc >> 1][0];

    // ph0: 12 reads; stage buf1.A-lo <- t1
    KV_RD_A(a0, 0);
    KV_RD_B(b0, 0);
    stage_half(At + t1 * 64, K, &As[1][0][0], tid);
    KV_BAR; KV_LGKM0;
    KV_MFMA(0, 0);
    KV_BAR;

    // ph1: 4 reads; stage buf1.A-hi <- t1
    KV_RD_B(b0, 1);
    stage_half(At + 128 * K + t1 * 64, K, &As[1][1][0], tid);
    KV_BAR; KV_LGKM0;
    KV_MFMA(0, 1);
    KV_BAR;

    // ph2: 8 reads; stage buf0.B-lo <- tn0
    KV_RD_A(a0, 1);
    if (tn0 < NT) stage_half(Bt + tn0 * 64, K, &Bs[0][0][0], tid);
    KV_BAR; KV_LGKM0;
    KV_MFMA(1, 0);
    KV_BAR;

    // ph3: stage buf0.B-hi <- tn0; derived vmcnt(4): completes ALL of t1
    if (tn0 < NT) stage_half(Bt + 128 * K + tn0 * 64, K, &Bs[0][1][0], tid);
    KV_BAR; KV_LGKM0;
    KV_MFMA(1, 1);
    if (i + 1 < NIT)
      asm volatile("s_waitcnt vmcnt(4)" ::: "memory");
    else
      asm volatile("s_waitcnt vmcnt(0)" ::: "memory");
    KV_BAR;

    // ph4: 12 reads (buf1); stage buf0.A-lo <- tn0
    KV_RD_A(a1, 0);
    KV_RD_B(b1, 0);
    if (tn0 < NT) stage_half(At + tn0 * 64, K, &As[0][0][0], tid);
    KV_BAR; KV_LGKM0;
    KV_MFMA(0, 0);
    KV_BAR;

    // ph5: 4 reads; stage buf0.A-hi <- tn0
    KV_RD_B(b1, 1);
    if (tn0 < NT) stage_half(At + 128 * K + tn0 * 64, K, &As[0][1][0], tid);
    KV_BAR; KV_LGKM0;
    KV_MFMA(0, 1);
    KV_BAR;

    // ph6: 8 reads; stage buf1.B-lo <- tn1
    KV_RD_A(a1, 1);
    if (tn1 < NT) stage_half(Bt + tn1 * 64, K, &Bs[1][0][0], tid);
    KV_BAR; KV_LGKM0;
    KV_MFMA(1, 0);
    KV_BAR;

    // ph7: stage buf1.B-hi <- tn1; derived vmcnt(4): completes ALL of tn0
    if (tn1 < NT) stage_half(Bt + 128 * K + tn1 * 64, K, &Bs[1][1][0], tid);
    KV_BAR; KV_LGKM0;
    KV_MFMA(1, 1);
    if (i + 1 < NIT) asm volatile("s_waitcnt vmcnt(4)" ::: "memory");
    KV_BAR;
  }

  // ---- epilogue: C/D layout col=lane&15, row=(lane>>4)*4+j ----
  if (col0 >= 1024) {  // V^T via LDS transpose (As+Bs contiguous 128 KiB)
    __syncthreads();
    uint16_t* smem = &As[0][0][0];
#pragma unroll
    for (int mi = 0; mi < 8; ++mi)
#pragma unroll
      for (int ni = 0; ni < 4; ++ni) {
        const int cc = wc * 64 + ni * 16 + lr;
        const int jjb = wr * 128 + mi * 16 + lg * 4;
        ushort4 o;
        o.x = f2bf(acc[mi][ni][0]);
        o.y = f2bf(acc[mi][ni][1]);
        o.z = f2bf(acc[mi][ni][2]);
        o.w = f2bf(acc[mi][ni][3]);
        *(ushort4*)&smem[cc * 256 + (jjb ^ ((cc & 7) << 3))] = o;
      }
    __syncthreads();
    const int b = row0 >> 10, jj0 = row0 & 1023;
#pragma unroll
    for (int k = 0; k < 16; ++k) {
      const int cc = k * 16 + (tid >> 5);
      const int jb = (tid & 31) * 8;
      bf16x8 v = *(const bf16x8*)&smem[cc * 256 + (jb ^ ((cc & 7) << 3))];
      *(bf16x8*)(Vp + (long long)b * 1048576 +
                 (long long)(col0 - 1024 + cc) * 1024 + jj0 + jb) = v;
    }
    return;
  }
#pragma unroll
  for (int mi = 0; mi < 8; ++mi)
#pragma unroll
    for (int ni = 0; ni < 4; ++ni) {
      const int row = row0 + wr * 128 + mi * 16 + lg * 4;
      const int col = col0 + wc * 64 + ni * 16 + lr;
#pragma unroll
      for (int j = 0; j < 4; ++j)
        Kp[(long long)(row + j) * 1024 + col] = f2bf(acc[mi][ni][j]);
    }
}

// ===========================================================================
// 128x128-tile A·B^T GEMM body: 4 waves, 64 KiB LDS (2 blocks/CU). [R11]
// EPI 0: C bf16. EPI 3: P'=exp(acc*scale) + Rpart partial rowsums.
// EPI 4: C fp32 = acc / R (R = sum of 8 Rpart).
// ===========================================================================
template <int EPI>
__device__ __forceinline__ void gemm128_body(
    const uint16_t* __restrict__ A, const uint16_t* __restrict__ B,
    void* __restrict__ C0, float* __restrict__ Rpart, int K, int N,
    long long sA, long long sB, long long sC, float scale) {
  __shared__ uint16_t smem[32768];
  __shared__ float RLDS[128];

  const int tid = threadIdx.x;
  const int lane = tid & 63;
  const int wid = tid >> 6;
  const int wr = wid >> 1, wc = wid & 1;
  const int lr = lane & 15, lg = lane >> 4;
  const int ch0 = lr & 7;

  int bx, by, bz;
  xcd_decode(bx, by, bz);
  const int row0 = by * 128;
  const int col0 = bx * 128;
  const int grow0 = bz * (N >= 1024 ? 1024 : N) + row0;
  const uint16_t* At = A + (long long)bz * sA + (long long)row0 * K;
  const uint16_t* Bt = B + (long long)bz * sB + (long long)col0 * K;

  const int NT = K >> 6;

  if (EPI == 4) {
    if (tid < 128) {
      float r = 0.f;
#pragma unroll
      for (int p = 0; p < 8; ++p) r += Rpart[p * 16384 + grow0 + tid];
      RLDS[tid] = 1.0f / r;
    }
  }

  stage128(At, K, smem, tid);
  stage128(Bt, K, smem + 16384, tid);
  stage128(At + 64, K, smem + 8192, tid);
  stage128(Bt + 64, K, smem + 24576, tid);
  asm volatile("s_waitcnt vmcnt(8)" ::: "memory");
  __builtin_amdgcn_s_barrier();

  f32x4 acc[4][4] = {};
  bf16x8 aA_[2][2], aB_[2][2], bF[4][2];

  {
    const uint8_t* sa = (const uint8_t*)smem;
#pragma unroll
    for (int mi = 0; mi < 2; ++mi)
#pragma unroll
      for (int kk = 0; kk < 2; ++kk)
        aA_[mi][kk] = *(const bf16x8*)(sa + (wr * 64 + mi * 16 + lr) * 128 +
                                       (((kk * 4 + lg) ^ ch0) << 4));
  }

  for (int t = 0; t < NT; ++t) {
    const uint8_t* sa = (const uint8_t*)(smem + (t & 1) * 8192);
    const uint8_t* sb = (const uint8_t*)(smem + 16384 + (t & 1) * 8192);

#pragma unroll
    for (int nj = 0; nj < 4; ++nj)
#pragma unroll
      for (int kk = 0; kk < 2; ++kk)
        bF[nj][kk] = *(const bf16x8*)(sb + (wc * 64 + nj * 16 + lr) * 128 +
                                      (((kk * 4 + lg) ^ ch0) << 4));
#pragma unroll
    for (int mi = 0; mi < 2; ++mi)
#pragma unroll
      for (int kk = 0; kk < 2; ++kk)
        aB_[mi][kk] = *(const bf16x8*)(sa + (wr * 64 + 32 + mi * 16 + lr) * 128 +
                                       (((kk * 4 + lg) ^ ch0) << 4));
    __builtin_amdgcn_s_setprio(1);
#pragma unroll
    for (int kk = 0; kk < 2; ++kk)
#pragma unroll
      for (int mi = 0; mi < 2; ++mi)
#pragma unroll
        for (int nj = 0; nj < 4; ++nj)
          acc[mi][nj] = __builtin_amdgcn_mfma_f32_16x16x32_bf16(
              aA_[mi][kk], bF[nj][kk], acc[mi][nj], 0, 0, 0);
    __builtin_amdgcn_s_setprio(0);
    if (t + 1 < NT) asm volatile("s_waitcnt vmcnt(4)" ::: "memory");
    asm volatile("s_waitcnt lgkmcnt(0)" ::: "memory");
    __builtin_amdgcn_s_barrier();

    if (t + 2 < NT) {
      stage128(At + (t + 2) * 64, K, smem + (t & 1) * 8192, tid);
      stage128(Bt + (t + 2) * 64, K, smem + 16384 + (t & 1) * 8192, tid);
    }
    if (t + 1 < NT) {
      const uint8_t* sa2 = (const uint8_t*)(smem + ((t + 1) & 1) * 8192);
#pragma unroll
      for (int mi = 0; mi < 2; ++mi)
#pragma unroll
        for (int kk = 0; kk < 2; ++kk)
          aA_[mi][kk] = *(const bf16x8*)(sa2 + (wr * 64 + mi * 16 + lr) * 128 +
                                         (((kk * 4 + lg) ^ ch0) << 4));
    }
    __builtin_amdgcn_s_setprio(1);
#pragma unroll
    for (int kk = 0; kk < 2; ++kk)
#pragma unroll
      for (int mi = 0; mi < 2; ++mi)
#pragma unroll
        for (int nj = 0; nj < 4; ++nj)
          acc[2 + mi][nj] = __builtin_amdgcn_mfma_f32_16x16x32_bf16(
              aB_[mi][kk], bF[nj][kk], acc[2 + mi][nj], 0, 0, 0);
    __builtin_amdgcn_s_setprio(0);
    if (t + 2 < NT)
      asm volatile("s_waitcnt vmcnt(8)" ::: "memory");
    else
      asm volatile("s_waitcnt vmcnt(0)" ::: "memory");
    __builtin_amdgcn_s_barrier();
  }

  if (EPI == 0) {
    uint16_t* C = (uint16_t*)C0;
#pragma unroll
    for (int mi = 0; mi < 4; ++mi)
#pragma unroll
      for (int ni = 0; ni < 4; ++ni) {
        const int row = row0 + wr * 64 + mi * 16 + lg * 4;
        const int col = col0 + wc * 64 + ni * 16 + lr;
#pragma unroll
        for (int j = 0; j < 4; ++j)
          C[(long long)(row + j) * N + col] = f2bf(acc[mi][ni][j]);
      }
  } else if (EPI == 3) {
    uint16_t* Pp = (uint16_t*)C0 + (long long)bz * sC;
    float rs[4][4];
#pragma unroll
    for (int mi = 0; mi < 4; ++mi) {
#pragma unroll
      for (int j = 0; j < 4; ++j) rs[mi][j] = 0.f;
#pragma unroll
      for (int ni = 0; ni < 4; ++ni) {
        const int row = row0 + wr * 64 + mi * 16 + lg * 4;
        const int col = col0 + wc * 64 + ni * 16 + lr;
#pragma unroll
        for (int j = 0; j < 4; ++j) {
          float e = __expf(acc[mi][ni][j] * scale);
          Pp[(long long)(row + j) * N + col] = f2bf(e);
          rs[mi][j] += e;
        }
      }
    }
#pragma unroll
    for (int o = 1; o < 16; o <<= 1)
#pragma unroll
      for (int mi = 0; mi < 4; ++mi)
#pragma unroll
        for (int j = 0; j < 4; ++j) rs[mi][j] += __shfl_xor(rs[mi][j], o, 64);
    __syncthreads();
    float* RS = (float*)smem;  // [2][128]
    if (lr == 0) {
#pragma unroll
      for (int mi = 0; mi < 4; ++mi)
#pragma unroll
        for (int j = 0; j < 4; ++j)
          RS[wc * 128 + wr * 64 + mi * 16 + lg * 4 + j] = rs[mi][j];
    }
    __syncthreads();
    if (tid < 128) Rpart[bx * 16384 + grow0 + tid] = RS[tid] + RS[128 + tid];
  } else {  // EPI == 4
    float* C = (float*)C0;
#pragma unroll
    for (int mi = 0; mi < 4; ++mi)
#pragma unroll
      for (int ni = 0; ni < 4; ++ni) {
        const int row = row0 + wr * 64 + mi * 16 + lg * 4;
        const int col = col0 + wc * 64 + ni * 16 + lr;
#pragma unroll
        for (int j = 0; j < 4; ++j) {
          const float rinv = RLDS[wr * 64 + mi * 16 + lg * 4 + j];
          C[(long long)bz * sC + (long long)(row + j) * N + col] =
              acc[mi][ni][j] * rinv;
        }
      }
  }
}

// ---- named GEMM sites ----
__global__ __launch_bounds__(256, 2) void g_qproj(const uint16_t* A,
                                                  const uint16_t* B,
                                                  uint16_t* C, int K, int N) {
  gemm128_body<0>(A, B, C, nullptr, K, N, 0, 0, 0, 1.0f);
}
__global__ __launch_bounds__(256, 2) void g_s(const uint16_t* A,
                                              const uint16_t* B, uint16_t* Pp,
                                              float* Rpart, int K,
                                              float scale) {
  gemm128_body<3>(A, B, Pp, Rpart, K, 1024, 1048576, 1048576, 1048576, scale);
}
__global__ __launch_bounds__(256, 2) void g_pv(const uint16_t* A,
                                               const uint16_t* B, float* C,
                                               float* Rpart, int K) {
  gemm128_body<4>(A, B, C, Rpart, K, 1024, 1048576, 1048576, 1048576, 1.0f);
}

extern "C" void kernel_launch(void* const* d_in, const int* in_sizes, int n_in,
                              void* d_out, int out_size, void* d_ws, size_t ws_size,
                              hipStream_t stream) {
  const float* x    = (const float*)d_in[0];
  const float* cond = (const float*)d_in[1];
  const float* Wq   = (const float*)d_in[2];
  const float* Wkv  = (const float*)d_in[3];
  float* out = (float*)d_out;

  uint8_t* ws = (uint8_t*)d_ws;
  const long long MiB = 1ll << 20;
  uint16_t* XB    = (uint16_t*)(ws + 0 * MiB);
  uint16_t* CB    = (uint16_t*)(ws + 32 * MiB);
  uint16_t* Pp    = (uint16_t*)(ws + 0 * MiB);    // overlays dead XB
  float*    Rpart = (float*)(ws + 32 * MiB);      // overlays dead CB
  uint16_t* WQB   = (uint16_t*)(ws + 64 * MiB);
  uint16_t* WKVB  = (uint16_t*)(ws + 66 * MiB);
  uint16_t* Q     = (uint16_t*)(ws + 70 * MiB);
  uint16_t* Kb    = (uint16_t*)(ws + 102 * MiB);
  uint16_t* VT    = (uint16_t*)(ws + 134 * MiB);

  // 1. fused conversions
  cvt_all<<<35840, 256, 0, stream>>>(x, cond, Wq, Wkv, XB, CB, WQB, WKVB);

  // 2. Q = XB @ WQB^T (1024 blocks, 2/CU)
  g_qproj<<<dim3(8, 128), 256, 0, stream>>>(XB, WQB, Q, 1024, 1024);
  // 3. KV = CB @ WKVB^T -> K, V^T (512 blocks, 8-phase schedule)
  g_kv<<<dim3(8, 64), 512, 0, stream>>>(CB, WKVB, Kb, VT, 1024);
  // 4. P' = exp(Q K^T / 32) + Rpart (1024 blocks)
  g_s<<<dim3(8, 8, 16), 256, 0, stream>>>(Q, Kb, Pp, Rpart, 1024, 0.03125f);
  // 5. out = (P' @ V) / R (1024 blocks)
  g_pv<<<dim3(8, 8, 16), 256, 0, stream>>>(Pp, VT, out, Rpart, 1024);
}

// Round 15
// 238.350 us; speedup vs baseline: 1.1465x; 1.0137x over previous
//
#include <hip/hip_runtime.h>
#include <stdint.h>

// ---------------------------------------------------------------------------
// CrossAttention (b=16, c=1024, dim=1024), fp32 in/out, bf16 MFMA internally.
//   1. cvt_all: x->XB, cond->CB, Wq->WQB, Wkv->WKVB (bf16)
//   2. g_qproj: Q = XB @ WQB^T            128^2 tiles, 1024 blocks (2/CU)
//   3. g_kv:    KV = CB @ WKVB^T -> K,V^T 256^2 tiles, 2-phase (920 TF)
//   4. g_s:     P' = exp(Q K^T/32), Rpart[8][16384] partial rowsums (128^2)
//   5. g_pv:    out = (P' @ V) / R        (128^2)
// R15 = revert to the verified R11 configuration (236.4us). Six schedule
// ports (4-phase, 8-phase x3, ring-4, lgkm-overlap) all landed at the same
// ~920 TF plateau; R14's corrected 8-phase was null (76.1 vs 74.7us). The
// 2-phase lgkm-pipelined body IS this structure family's ceiling. All
// documented plain-HIP levers applied: XCD swizzle (T1), XOR-swizzled LDS
// (T2, conflicts ~0), counted vmcnt (T4), setprio (T5), no-max softmax
// fusion, V^T LDS-transpose epilogue, deterministic Rpart reduction.
// ---------------------------------------------------------------------------

typedef __bf16 bf16_t;
typedef bf16_t bf16x8 __attribute__((ext_vector_type(8)));
typedef float f32x4 __attribute__((ext_vector_type(4)));

#define AS1 __attribute__((address_space(1)))
#define AS3 __attribute__((address_space(3)))

__device__ __forceinline__ uint16_t f2bf(float f) {
  bf16_t h = (bf16_t)f;  // RNE
  return __builtin_bit_cast(uint16_t, h);
}

// ---- fused fp32 -> bf16 conversion for all 4 tensors, float4-vectorized ----
// total float4 = (16777216 + 16777216 + 1048576 + 2097152)/4 = 9,175,040
__global__ __launch_bounds__(256) void cvt_all(
    const float* __restrict__ x, const float* __restrict__ c,
    const float* __restrict__ wq, const float* __restrict__ wkv,
    uint16_t* __restrict__ XB, uint16_t* __restrict__ CB,
    uint16_t* __restrict__ WQB, uint16_t* __restrict__ WKVB) {
  long i = (long)blockIdx.x * 256 + threadIdx.x;
  if (i >= 9175040) return;
  const float* src;
  uint16_t* dst;
  long off;
  if (i < 4194304) { src = x; dst = XB; off = i; }
  else if (i < 8388608) { src = c; dst = CB; off = i - 4194304; }
  else if (i < 8650752) { src = wq; dst = WQB; off = i - 8388608; }
  else { src = wkv; dst = WKVB; off = i - 8650752; }
  float4 v = ((const float4*)src)[off];
  ushort4 o;
  o.x = f2bf(v.x); o.y = f2bf(v.y); o.z = f2bf(v.z); o.w = f2bf(v.w);
  ((ushort4*)dst)[off] = o;
}

// ---- stage one 256x64 bf16 K-tile (32 KiB), 512 threads, 4 loads/thread ----
// LDS dest linear (global_load_lds); SOURCE chunk-XOR pre-swizzled (rule #21)
// so readers use chunk^=(row&7), conflict-free.
__device__ __forceinline__ void stage_tile(const uint16_t* __restrict__ g,
                                           int ldK, uint16_t* lds, int tid) {
#pragma unroll
  for (int i = 0; i < 4; ++i) {
    int cix = i * 512 + tid;
    int row = cix >> 3;
    int ch = cix & 7;
    int sch = ch ^ (row & 7);
    const uint16_t* gp = g + row * ldK + sch * 8;
    __builtin_amdgcn_global_load_lds((AS1 void*)gp,
                                     (AS3 void*)((uint8_t*)lds + cix * 16), 16,
                                     0, 0);
  }
}

// ---- stage one 128x64 bf16 K-tile (16 KiB), 256 threads, 4 loads/thread ----
__device__ __forceinline__ void stage128(const uint16_t* __restrict__ g,
                                         int ldK, uint16_t* lds, int tid) {
#pragma unroll
  for (int i = 0; i < 4; ++i) {
    int cix = i * 256 + tid;
    int row = cix >> 3;
    int ch = cix & 7;
    int sch = ch ^ (row & 7);
    const uint16_t* gp = g + row * ldK + sch * 8;
    __builtin_amdgcn_global_load_lds((AS1 void*)gp,
                                     (AS3 void*)((uint8_t*)lds + cix * 16), 16,
                                     0, 0);
  }
}

// ---- XCD-chunked bijective block swizzle (nwg % 8 == 0 for all grids) ----
__device__ __forceinline__ void xcd_decode(int& bx, int& by, int& bz) {
  const int gx = gridDim.x, gy = gridDim.y;
  const int nwg = gx * gy * gridDim.z;
  int fid = blockIdx.x + gx * (blockIdx.y + gy * blockIdx.z);
  int swz = (fid & 7) * (nwg >> 3) + (fid >> 3);
  bx = swz % gx;
  int rem = swz / gx;
  by = rem % gy;
  bz = rem / gy;
}

// ===========================================================================
// g_kv: 256x256-tile GEMM, 8 waves, 128 KiB LDS, 2-phase lgkm-pipelined.
// kv-split epilogue (col<1024 -> K row-major; col>=1024 -> V^T transpose).
// ===========================================================================
__global__ __launch_bounds__(512, 2) void g_kv(
    const uint16_t* __restrict__ A, const uint16_t* __restrict__ B,
    uint16_t* __restrict__ Kp, uint16_t* __restrict__ Vp, int K) {
  __shared__ uint16_t smem[65536];

  const int tid = threadIdx.x;
  const int lane = tid & 63;
  const int wid = tid >> 6;
  const int wr = wid >> 2;    // 0..1
  const int wc = wid & 3;     // 0..3
  const int lr = lane & 15, lg = lane >> 4;
  const int ch0 = lr & 7;

  int bx, by, bz;
  xcd_decode(bx, by, bz);
  const int row0 = by * 256;
  const int col0 = bx * 256;
  const uint16_t* At = A + (long long)row0 * K;
  const uint16_t* Bt = B + (long long)col0 * K;

  const int NT = K >> 6;

  stage_tile(At, K, smem, tid);
  stage_tile(Bt, K, smem + 32768, tid);
  stage_tile(At + 64, K, smem + 16384, tid);
  stage_tile(Bt + 64, K, smem + 49152, tid);
  asm volatile("s_waitcnt vmcnt(8)" ::: "memory");
  __builtin_amdgcn_s_barrier();

  f32x4 acc[8][4] = {};
  bf16x8 aA_[4][2], aB_[4][2], bF[4][2];

  {
    const uint8_t* sa = (const uint8_t*)smem;
#pragma unroll
    for (int mi = 0; mi < 4; ++mi)
#pragma unroll
      for (int kk = 0; kk < 2; ++kk)
        aA_[mi][kk] = *(const bf16x8*)(sa + (wr * 128 + mi * 16 + lr) * 128 +
                                       (((kk * 4 + lg) ^ ch0) << 4));
  }

  for (int t = 0; t < NT; ++t) {
    const uint8_t* sa = (const uint8_t*)(smem + (t & 1) * 16384);
    const uint8_t* sb = (const uint8_t*)(smem + 32768 + (t & 1) * 16384);

    // phase (t,0): MFMA {aA_, bF}; prefetch aB_ (stays lgkm-outstanding)
#pragma unroll
    for (int nj = 0; nj < 4; ++nj)
#pragma unroll
      for (int kk = 0; kk < 2; ++kk)
        bF[nj][kk] = *(const bf16x8*)(sb + (wc * 64 + nj * 16 + lr) * 128 +
                                      (((kk * 4 + lg) ^ ch0) << 4));
#pragma unroll
    for (int mi = 0; mi < 4; ++mi)
#pragma unroll
      for (int kk = 0; kk < 2; ++kk)
        aB_[mi][kk] = *(const bf16x8*)(sa + (wr * 128 + 64 + mi * 16 + lr) * 128 +
                                       (((kk * 4 + lg) ^ ch0) << 4));
    __builtin_amdgcn_s_setprio(1);
#pragma unroll
    for (int kk = 0; kk < 2; ++kk)
#pragma unroll
      for (int mi = 0; mi < 4; ++mi)
#pragma unroll
        for (int nj = 0; nj < 4; ++nj)
          acc[mi][nj] = __builtin_amdgcn_mfma_f32_16x16x32_bf16(
              aA_[mi][kk], bF[nj][kk], acc[mi][nj], 0, 0, 0);
    __builtin_amdgcn_s_setprio(0);
    if (t + 1 < NT) asm volatile("s_waitcnt vmcnt(4)" ::: "memory");
    asm volatile("s_waitcnt lgkmcnt(0)" ::: "memory");  // WAR for ph(t,1) stages
    __builtin_amdgcn_s_barrier();

    // phase (t,1): stages; MFMA {aB_, bF}; refill aA_ from buf[(t+1)&1]
    if (t + 2 < NT) {
      stage_tile(At + (t + 2) * 64, K, smem + (t & 1) * 16384, tid);
      stage_tile(Bt + (t + 2) * 64, K, smem + 32768 + (t & 1) * 16384, tid);
    }
    if (t + 1 < NT) {
      const uint8_t* sa2 = (const uint8_t*)(smem + ((t + 1) & 1) * 16384);
#pragma unroll
      for (int mi = 0; mi < 4; ++mi)
#pragma unroll
        for (int kk = 0; kk < 2; ++kk)
          aA_[mi][kk] = *(const bf16x8*)(sa2 + (wr * 128 + mi * 16 + lr) * 128 +
                                         (((kk * 4 + lg) ^ ch0) << 4));
    }
    __builtin_amdgcn_s_setprio(1);
#pragma unroll
    for (int kk = 0; kk < 2; ++kk)
#pragma unroll
      for (int mi = 0; mi < 4; ++mi)
#pragma unroll
        for (int nj = 0; nj < 4; ++nj)
          acc[4 + mi][nj] = __builtin_amdgcn_mfma_f32_16x16x32_bf16(
              aB_[mi][kk], bF[nj][kk], acc[4 + mi][nj], 0, 0, 0);
    __builtin_amdgcn_s_setprio(0);
    if (t + 2 < NT)
      asm volatile("s_waitcnt vmcnt(8)" ::: "memory");
    else
      asm volatile("s_waitcnt vmcnt(0)" ::: "memory");
    __builtin_amdgcn_s_barrier();
  }

  // epilogue: C/D layout col=lane&15, row=(lane>>4)*4+j
  if (col0 >= 1024) {
    __syncthreads();
#pragma unroll
    for (int mi = 0; mi < 8; ++mi)
#pragma unroll
      for (int ni = 0; ni < 4; ++ni) {
        const int cc = wc * 64 + ni * 16 + lr;
        const int jjb = wr * 128 + mi * 16 + lg * 4;
        ushort4 o;
        o.x = f2bf(acc[mi][ni][0]);
        o.y = f2bf(acc[mi][ni][1]);
        o.z = f2bf(acc[mi][ni][2]);
        o.w = f2bf(acc[mi][ni][3]);
        *(ushort4*)&smem[cc * 256 + (jjb ^ ((cc & 7) << 3))] = o;
      }
    __syncthreads();
    const int b = row0 >> 10, jj0 = row0 & 1023;
#pragma unroll
    for (int k = 0; k < 16; ++k) {
      const int cc = k * 16 + (tid >> 5);
      const int jb = (tid & 31) * 8;
      bf16x8 v = *(const bf16x8*)&smem[cc * 256 + (jb ^ ((cc & 7) << 3))];
      *(bf16x8*)(Vp + (long long)b * 1048576 +
                 (long long)(col0 - 1024 + cc) * 1024 + jj0 + jb) = v;
    }
    return;
  }
#pragma unroll
  for (int mi = 0; mi < 8; ++mi)
#pragma unroll
    for (int ni = 0; ni < 4; ++ni) {
      const int row = row0 + wr * 128 + mi * 16 + lg * 4;
      const int col = col0 + wc * 64 + ni * 16 + lr;
#pragma unroll
      for (int j = 0; j < 4; ++j)
        Kp[(long long)(row + j) * 1024 + col] = f2bf(acc[mi][ni][j]);
    }
}

// ===========================================================================
// 128x128-tile A·B^T GEMM body: 4 waves, 64 KiB LDS (2 blocks/CU).
// EPI 0: C bf16. EPI 3: P'=exp(acc*scale) + Rpart partial rowsums.
// EPI 4: C fp32 = acc / R (R = sum of 8 Rpart).
// ===========================================================================
template <int EPI>
__device__ __forceinline__ void gemm128_body(
    const uint16_t* __restrict__ A, const uint16_t* __restrict__ B,
    void* __restrict__ C0, float* __restrict__ Rpart, int K, int N,
    long long sA, long long sB, long long sC, float scale) {
  __shared__ uint16_t smem[32768];
  __shared__ float RLDS[128];

  const int tid = threadIdx.x;
  const int lane = tid & 63;
  const int wid = tid >> 6;
  const int wr = wid >> 1, wc = wid & 1;
  const int lr = lane & 15, lg = lane >> 4;
  const int ch0 = lr & 7;

  int bx, by, bz;
  xcd_decode(bx, by, bz);
  const int row0 = by * 128;
  const int col0 = bx * 128;
  const int grow0 = bz * (N >= 1024 ? 1024 : N) + row0;
  const uint16_t* At = A + (long long)bz * sA + (long long)row0 * K;
  const uint16_t* Bt = B + (long long)bz * sB + (long long)col0 * K;

  const int NT = K >> 6;

  if (EPI == 4) {
    if (tid < 128) {
      float r = 0.f;
#pragma unroll
      for (int p = 0; p < 8; ++p) r += Rpart[p * 16384 + grow0 + tid];
      RLDS[tid] = 1.0f / r;
    }
  }

  stage128(At, K, smem, tid);
  stage128(Bt, K, smem + 16384, tid);
  stage128(At + 64, K, smem + 8192, tid);
  stage128(Bt + 64, K, smem + 24576, tid);
  asm volatile("s_waitcnt vmcnt(8)" ::: "memory");
  __builtin_amdgcn_s_barrier();

  f32x4 acc[4][4] = {};
  bf16x8 aA_[2][2], aB_[2][2], bF[4][2];

  {
    const uint8_t* sa = (const uint8_t*)smem;
#pragma unroll
    for (int mi = 0; mi < 2; ++mi)
#pragma unroll
      for (int kk = 0; kk < 2; ++kk)
        aA_[mi][kk] = *(const bf16x8*)(sa + (wr * 64 + mi * 16 + lr) * 128 +
                                       (((kk * 4 + lg) ^ ch0) << 4));
  }

  for (int t = 0; t < NT; ++t) {
    const uint8_t* sa = (const uint8_t*)(smem + (t & 1) * 8192);
    const uint8_t* sb = (const uint8_t*)(smem + 16384 + (t & 1) * 8192);

#pragma unroll
    for (int nj = 0; nj < 4; ++nj)
#pragma unroll
      for (int kk = 0; kk < 2; ++kk)
        bF[nj][kk] = *(const bf16x8*)(sb + (wc * 64 + nj * 16 + lr) * 128 +
                                      (((kk * 4 + lg) ^ ch0) << 4));
#pragma unroll
    for (int mi = 0; mi < 2; ++mi)
#pragma unroll
      for (int kk = 0; kk < 2; ++kk)
        aB_[mi][kk] = *(const bf16x8*)(sa + (wr * 64 + 32 + mi * 16 + lr) * 128 +
                                       (((kk * 4 + lg) ^ ch0) << 4));
    __builtin_amdgcn_s_setprio(1);
#pragma unroll
    for (int kk = 0; kk < 2; ++kk)
#pragma unroll
      for (int mi = 0; mi < 2; ++mi)
#pragma unroll
        for (int nj = 0; nj < 4; ++nj)
          acc[mi][nj] = __builtin_amdgcn_mfma_f32_16x16x32_bf16(
              aA_[mi][kk], bF[nj][kk], acc[mi][nj], 0, 0, 0);
    __builtin_amdgcn_s_setprio(0);
    if (t + 1 < NT) asm volatile("s_waitcnt vmcnt(4)" ::: "memory");
    asm volatile("s_waitcnt lgkmcnt(0)" ::: "memory");
    __builtin_amdgcn_s_barrier();

    if (t + 2 < NT) {
      stage128(At + (t + 2) * 64, K, smem + (t & 1) * 8192, tid);
      stage128(Bt + (t + 2) * 64, K, smem + 16384 + (t & 1) * 8192, tid);
    }
    if (t + 1 < NT) {
      const uint8_t* sa2 = (const uint8_t*)(smem + ((t + 1) & 1) * 8192);
#pragma unroll
      for (int mi = 0; mi < 2; ++mi)
#pragma unroll
        for (int kk = 0; kk < 2; ++kk)
          aA_[mi][kk] = *(const bf16x8*)(sa2 + (wr * 64 + mi * 16 + lr) * 128 +
                                         (((kk * 4 + lg) ^ ch0) << 4));
    }
    __builtin_amdgcn_s_setprio(1);
#pragma unroll
    for (int kk = 0; kk < 2; ++kk)
#pragma unroll
      for (int mi = 0; mi < 2; ++mi)
#pragma unroll
        for (int nj = 0; nj < 4; ++nj)
          acc[2 + mi][nj] = __builtin_amdgcn_mfma_f32_16x16x32_bf16(
              aB_[mi][kk], bF[nj][kk], acc[2 + mi][nj], 0, 0, 0);
    __builtin_amdgcn_s_setprio(0);
    if (t + 2 < NT)
      asm volatile("s_waitcnt vmcnt(8)" ::: "memory");
    else
      asm volatile("s_waitcnt vmcnt(0)" ::: "memory");
    __builtin_amdgcn_s_barrier();
  }

  if (EPI == 0) {
    uint16_t* C = (uint16_t*)C0;
#pragma unroll
    for (int mi = 0; mi < 4; ++mi)
#pragma unroll
      for (int ni = 0; ni < 4; ++ni) {
        const int row = row0 + wr * 64 + mi * 16 + lg * 4;
        const int col = col0 + wc * 64 + ni * 16 + lr;
#pragma unroll
        for (int j = 0; j < 4; ++j)
          C[(long long)(row + j) * N + col] = f2bf(acc[mi][ni][j]);
      }
  } else if (EPI == 3) {
    uint16_t* Pp = (uint16_t*)C0 + (long long)bz * sC;
    float rs[4][4];
#pragma unroll
    for (int mi = 0; mi < 4; ++mi) {
#pragma unroll
      for (int j = 0; j < 4; ++j) rs[mi][j] = 0.f;
#pragma unroll
      for (int ni = 0; ni < 4; ++ni) {
        const int row = row0 + wr * 64 + mi * 16 + lg * 4;
        const int col = col0 + wc * 64 + ni * 16 + lr;
#pragma unroll
        for (int j = 0; j < 4; ++j) {
          float e = __expf(acc[mi][ni][j] * scale);
          Pp[(long long)(row + j) * N + col] = f2bf(e);
          rs[mi][j] += e;
        }
      }
    }
#pragma unroll
    for (int o = 1; o < 16; o <<= 1)
#pragma unroll
      for (int mi = 0; mi < 4; ++mi)
#pragma unroll
        for (int j = 0; j < 4; ++j) rs[mi][j] += __shfl_xor(rs[mi][j], o, 64);
    __syncthreads();
    float* RS = (float*)smem;  // [2][128]
    if (lr == 0) {
#pragma unroll
      for (int mi = 0; mi < 4; ++mi)
#pragma unroll
        for (int j = 0; j < 4; ++j)
          RS[wc * 128 + wr * 64 + mi * 16 + lg * 4 + j] = rs[mi][j];
    }
    __syncthreads();
    if (tid < 128) Rpart[bx * 16384 + grow0 + tid] = RS[tid] + RS[128 + tid];
  } else {  // EPI == 4
    float* C = (float*)C0;
#pragma unroll
    for (int mi = 0; mi < 4; ++mi)
#pragma unroll
      for (int ni = 0; ni < 4; ++ni) {
        const int row = row0 + wr * 64 + mi * 16 + lg * 4;
        const int col = col0 + wc * 64 + ni * 16 + lr;
#pragma unroll
        for (int j = 0; j < 4; ++j) {
          const float rinv = RLDS[wr * 64 + mi * 16 + lg * 4 + j];
          C[(long long)bz * sC + (long long)(row + j) * N + col] =
              acc[mi][ni][j] * rinv;
        }
      }
  }
}

// ---- named GEMM sites ----
__global__ __launch_bounds__(256, 2) void g_qproj(const uint16_t* A,
                                                  const uint16_t* B,
                                                  uint16_t* C, int K, int N) {
  gemm128_body<0>(A, B, C, nullptr, K, N, 0, 0, 0, 1.0f);
}
__global__ __launch_bounds__(256, 2) void g_s(const uint16_t* A,
                                              const uint16_t* B, uint16_t* Pp,
                                              float* Rpart, int K,
                                              float scale) {
  gemm128_body<3>(A, B, Pp, Rpart, K, 1024, 1048576, 1048576, 1048576, scale);
}
__global__ __launch_bounds__(256, 2) void g_pv(const uint16_t* A,
                                               const uint16_t* B, float* C,
                                               float* Rpart, int K) {
  gemm128_body<4>(A, B, C, Rpart, K, 1024, 1048576, 1048576, 1048576, 1.0f);
}

extern "C" void kernel_launch(void* const* d_in, const int* in_sizes, int n_in,
                              void* d_out, int out_size, void* d_ws, size_t ws_size,
                              hipStream_t stream) {
  const float* x    = (const float*)d_in[0];
  const float* cond = (const float*)d_in[1];
  const float* Wq   = (const float*)d_in[2];
  const float* Wkv  = (const float*)d_in[3];
  float* out = (float*)d_out;

  uint8_t* ws = (uint8_t*)d_ws;
  const long long MiB = 1ll << 20;
  uint16_t* XB    = (uint16_t*)(ws + 0 * MiB);
  uint16_t* CB    = (uint16_t*)(ws + 32 * MiB);
  uint16_t* Pp    = (uint16_t*)(ws + 0 * MiB);    // overlays dead XB
  float*    Rpart = (float*)(ws + 32 * MiB);      // overlays dead CB
  uint16_t* WQB   = (uint16_t*)(ws + 64 * MiB);
  uint16_t* WKVB  = (uint16_t*)(ws + 66 * MiB);
  uint16_t* Q     = (uint16_t*)(ws + 70 * MiB);
  uint16_t* Kb    = (uint16_t*)(ws + 102 * MiB);
  uint16_t* VT    = (uint16_t*)(ws + 134 * MiB);

  // 1. fused conversions
  cvt_all<<<35840, 256, 0, stream>>>(x, cond, Wq, Wkv, XB, CB, WQB, WKVB);

  // 2. Q = XB @ WQB^T (1024 blocks, 2/CU)
  g_qproj<<<dim3(8, 128), 256, 0, stream>>>(XB, WQB, Q, 1024, 1024);
  // 3. KV = CB @ WKVB^T -> K, V^T (512 blocks, 2-phase 256^2)
  g_kv<<<dim3(8, 64), 512, 0, stream>>>(CB, WKVB, Kb, VT, 1024);
  // 4. P' = exp(Q K^T / 32) + Rpart (1024 blocks)
  g_s<<<dim3(8, 8, 16), 256, 0, stream>>>(Q, Kb, Pp, Rpart, 1024, 0.03125f);
  // 5. out = (P' @ V) / R (1024 blocks)
  g_pv<<<dim3(8, 8, 16), 256, 0, stream>>>(Pp, VT, out, Rpart, 1024);
}